// Round 6
// baseline (1764.865 us; speedup 1.0000x reference)
//
#include <hip/hip_runtime.h>
#include <cmath>

// ---------------------------------------------------------------------------
// CausalStream: conv frontend (4 dilated causal convs) -> folded enc+ip GEMM
// -> sequential gelu-SSM scan -> pooled/cls heads + metanet/frontdoor path.
// B=32, D=6, T=2048, FH=128, ENC=128, H=256, CONF=64, NC=10, K=5
// ---------------------------------------------------------------------------

typedef __bf16 bf16_t;
typedef bf16_t bf16x8 __attribute__((ext_vector_type(8)));
typedef bf16_t bf16x4 __attribute__((ext_vector_type(4)));
typedef float f32x4 __attribute__((ext_vector_type(4)));

__device__ __forceinline__ f32x4 mfma16(bf16x8 a, bf16x8 b, f32x4 c) {
  return __builtin_amdgcn_mfma_f32_16x16x32_bf16(a, b, c, 0, 0, 0);
}
// tanh-form gelu, constants folded for exp2: gelu(x) = x / (1 + 2^(x*(a+b*x^2)))
// |err| <= ~3.4e-4 (below bf16 h-storage rounding; R3-R5 passed with this).
__device__ __forceinline__ float gelu_fast(float x) {
  float x2 = x * x;
  float p = __builtin_fmaf(x2, -0.10295219f, -2.3022081278f);
  float e = __builtin_amdgcn_exp2f(x * p);
  return x * __builtin_amdgcn_rcpf(1.f + e);
}
__device__ __forceinline__ float bf2f(unsigned short us) {
  return __uint_as_float(((unsigned)us) << 16);
}

// ---------------------------------------------------------------------------
// k_prep: conv-weight repack (blocks 0..975) + enc/ip fold (blocks 976..1103).
// repack: (O,I,K) fp32 -> bf16 [ks][o][i] (conv0 padded to K=32).
// wce: W_ce[h][c] = ip_w[h]@enc_w[:,c]; b_ce = ip_w@enc_b + ip_b + state_bias.
// ---------------------------------------------------------------------------
__global__ void k_prep(const float* __restrict__ w0, const float* __restrict__ w1,
                       const float* __restrict__ w2, const float* __restrict__ w3,
                       bf16_t* __restrict__ wb0, bf16_t* __restrict__ wb1,
                       bf16_t* __restrict__ wb2, bf16_t* __restrict__ wb3,
                       const float* __restrict__ ip_w, const float* __restrict__ enc_w,
                       const float* __restrict__ enc_b, const float* __restrict__ ip_b,
                       const float* __restrict__ sbias, bf16_t* __restrict__ wce,
                       float* __restrict__ bce) {
  if (blockIdx.x >= 976) {
    const int hb = blockIdx.x - 976;
    const int h = hb * 2 + (threadIdx.x >> 7), c = threadIdx.x & 127;
    float s = 0.f;
    for (int e = 0; e < 128; ++e) s += ip_w[h * 128 + e] * enc_w[e * 128 + c];
    wce[h * 128 + c] = (bf16_t)s;
    if (c == 0) {
      float bv = 0.f;
      for (int e = 0; e < 128; ++e) bv += ip_w[h * 128 + e] * enc_b[e];
      bce[h] = bv + ip_b[h] + sbias[h];
    }
    return;
  }
  int idx = blockIdx.x * 256 + threadIdx.x;
  if (idx < 128 * 32) {
    int o = idx >> 5, k = idx & 31;
    float v = 0.f;
    if (k < 30) { int i = k / 5, kk = k - i * 5; v = w0[(o * 6 + i) * 5 + kk]; }
    wb0[idx] = (bf16_t)v;
    return;
  }
  int e = idx - 128 * 32;
  if (e < 3 * 5 * 128 * 128) {
    int layer = e / (5 * 128 * 128);
    int r = e - layer * (5 * 128 * 128);
    int ks = r / 16384;
    int o = (r >> 7) & 127;
    int i = r & 127;
    const float* w = layer == 0 ? w1 : layer == 1 ? w2 : w3;
    bf16_t* wb = layer == 0 ? wb1 : layer == 1 ? wb2 : wb3;
    wb[r] = (bf16_t)w[(o * 128 + i) * 5 + ks];
  }
}

// ---------------------------------------------------------------------------
// conv0: M (B,6,T) fp32 -> act (B,T,128) bf16.  K-dim = 6*5 padded to 32.
// ---------------------------------------------------------------------------
__global__ __launch_bounds__(256) void k_conv0(const float* __restrict__ M,
                                               const bf16_t* __restrict__ wb0,
                                               const float* __restrict__ b0,
                                               bf16_t* __restrict__ out) {
  __shared__ float raw[6][136];
  __shared__ bf16_t Xe[128 * 40];
  const int tid = threadIdx.x;
  const int b = blockIdx.y, t0 = blockIdx.x * 128;
  for (int id = tid; id < 6 * 132; id += 256) {
    int i = id / 132, j = id - i * 132;
    int t = t0 - 4 + j;
    raw[i][j] = (t >= 0) ? M[((size_t)b * 6 + i) * 2048 + t] : 0.f;
  }
  __syncthreads();
  for (int id = tid; id < 128 * 32; id += 256) {
    int tl = id >> 5, k = id & 31;
    float v = 0.f;
    if (k < 30) { int i = k / 5, kk = k - i * 5; v = raw[i][tl + kk]; }
    Xe[tl * 40 + k] = (bf16_t)v;
  }
  __syncthreads();
  const int w = tid >> 6, lane = tid & 63, q = lane >> 4, l15 = lane & 15;
  const int k0 = q * 8;
  const f32x4 z4 = {0.f, 0.f, 0.f, 0.f};
  f32x4 acc[2][8];
#pragma unroll
  for (int mt = 0; mt < 2; ++mt)
#pragma unroll
    for (int nt = 0; nt < 8; ++nt) acc[mt][nt] = z4;
  bf16x8 af[2];
#pragma unroll
  for (int mt = 0; mt < 2; ++mt)
    af[mt] = *(const bf16x8*)&Xe[(w * 32 + mt * 16 + l15) * 40 + k0];
#pragma unroll
  for (int nt = 0; nt < 8; ++nt) {
    bf16x8 bf = *(const bf16x8*)&wb0[(nt * 16 + l15) * 32 + k0];
#pragma unroll
    for (int mt = 0; mt < 2; ++mt) acc[mt][nt] = mfma16(af[mt], bf, acc[mt][nt]);
  }
#pragma unroll
  for (int nt = 0; nt < 8; ++nt) {
    const int o = nt * 16 + l15;
    const float bias = b0[o];
#pragma unroll
    for (int mt = 0; mt < 2; ++mt) {
#pragma unroll
      for (int r = 0; r < 4; ++r) {
        int t = t0 + w * 32 + mt * 16 + q * 4 + r;
        float v = acc[mt][nt][r] + bias;
        out[((size_t)b * 2048 + t) * 128 + o] = (bf16_t)(v > 0.f ? v : 0.f);
      }
    }
  }
}

// ---------------------------------------------------------------------------
// conv layers 1..3: act (B,T,128) bf16 -> act (B,T,128) bf16, kernel 5,
// dilation DIL, causal.  Implicit GEMM: per ks shift, K=128 channel GEMM.
// ---------------------------------------------------------------------------
template <int DIL>
__global__ __launch_bounds__(256) void k_conv(const bf16_t* __restrict__ in,
                                              const bf16_t* __restrict__ wb,
                                              const float* __restrict__ bias,
                                              bf16_t* __restrict__ out) {
  __shared__ bf16_t Xs[160 * 136];  // rows r <-> t = t0 + r - 32, pitch-padded
  const int tid = threadIdx.x;
  const int b = blockIdx.y, t0 = blockIdx.x * 128;
  const bf16_t* src = in + (size_t)b * 2048 * 128;
  for (int id = tid; id < 160 * 16; id += 256) {
    int r = id >> 4, ck = id & 15;
    int t = t0 + r - 32;
    int4 v = make_int4(0, 0, 0, 0);
    if (t >= 0) v = *(const int4*)(src + (size_t)t * 128 + ck * 8);
    *(int4*)&Xs[r * 136 + ck * 8] = v;
  }
  __syncthreads();
  const int w = tid >> 6, lane = tid & 63, q = lane >> 4, l15 = lane & 15;
  const f32x4 z4 = {0.f, 0.f, 0.f, 0.f};
  f32x4 acc[2][8];
#pragma unroll
  for (int mt = 0; mt < 2; ++mt)
#pragma unroll
    for (int nt = 0; nt < 8; ++nt) acc[mt][nt] = z4;
#pragma unroll
  for (int ks = 0; ks < 5; ++ks) {
    const int shift = (4 - ks) * DIL;
#pragma unroll
    for (int kt = 0; kt < 4; ++kt) {
      const int k0 = kt * 32 + q * 8;
      bf16x8 af[2];
#pragma unroll
      for (int mt = 0; mt < 2; ++mt)
        af[mt] = *(const bf16x8*)&Xs[(32 + w * 32 + mt * 16 + l15 - shift) * 136 + k0];
#pragma unroll
      for (int nt = 0; nt < 8; ++nt) {
        bf16x8 bf = *(const bf16x8*)&wb[((size_t)ks * 128 + nt * 16 + l15) * 128 + k0];
#pragma unroll
        for (int mt = 0; mt < 2; ++mt) acc[mt][nt] = mfma16(af[mt], bf, acc[mt][nt]);
      }
    }
  }
#pragma unroll
  for (int nt = 0; nt < 8; ++nt) {
    const int o = nt * 16 + l15;
    const float bv = bias[o];
#pragma unroll
    for (int mt = 0; mt < 2; ++mt) {
#pragma unroll
      for (int r = 0; r < 4; ++r) {
        int t = t0 + w * 32 + mt * 16 + q * 4 + r;
        float v = acc[mt][nt][r] + bv;
        out[((size_t)b * 2048 + t) * 128 + o] = (bf16_t)(v > 0.f ? v : 0.f);
      }
    }
  }
}

// ---------------------------------------------------------------------------
// u-GEMM: u[b][t][h] = act3[b][t][:] @ W_ce[h][:] + b_ce[h]   (bf16 out)
// ---------------------------------------------------------------------------
__global__ __launch_bounds__(256) void k_ugemm(const bf16_t* __restrict__ in,
                                               const bf16_t* __restrict__ wce,
                                               const float* __restrict__ bce,
                                               bf16_t* __restrict__ u) {
  __shared__ bf16_t Xs[128 * 136];
  const int tid = threadIdx.x;
  const int b = blockIdx.y, t0 = blockIdx.x * 128, hh = blockIdx.z;
  const bf16_t* src = in + (size_t)b * 2048 * 128;
  for (int id = tid; id < 128 * 16; id += 256) {
    int r = id >> 4, ck = id & 15;
    *(int4*)&Xs[r * 136 + ck * 8] = *(const int4*)(src + (size_t)(t0 + r) * 128 + ck * 8);
  }
  __syncthreads();
  const int w = tid >> 6, lane = tid & 63, q = lane >> 4, l15 = lane & 15;
  const f32x4 z4 = {0.f, 0.f, 0.f, 0.f};
  f32x4 acc[2][8];
#pragma unroll
  for (int mt = 0; mt < 2; ++mt)
#pragma unroll
    for (int nt = 0; nt < 8; ++nt) acc[mt][nt] = z4;
#pragma unroll
  for (int kt = 0; kt < 4; ++kt) {
    const int k0 = kt * 32 + q * 8;
    bf16x8 af[2];
#pragma unroll
    for (int mt = 0; mt < 2; ++mt)
      af[mt] = *(const bf16x8*)&Xs[(w * 32 + mt * 16 + l15) * 136 + k0];
#pragma unroll
    for (int nt = 0; nt < 8; ++nt) {
      bf16x8 bf = *(const bf16x8*)&wce[((size_t)hh * 128 + nt * 16 + l15) * 128 + k0];
#pragma unroll
      for (int mt = 0; mt < 2; ++mt) acc[mt][nt] = mfma16(af[mt], bf, acc[mt][nt]);
    }
  }
#pragma unroll
  for (int nt = 0; nt < 8; ++nt) {
    const int h = hh * 128 + nt * 16 + l15;
    const float bv = bce[h];
#pragma unroll
    for (int mt = 0; mt < 2; ++mt) {
#pragma unroll
      for (int r = 0; r < 4; ++r) {
        int t = t0 + w * 32 + mt * 16 + q * 4 + r;
        u[((size_t)b * 2048 + t) * 256 + h] = (bf16_t)(acc[mt][nt][r] + bv);
      }
    }
  }
}

// ---------------------------------------------------------------------------
// Sequential scan v6: 16 samples/block, 2 blocks, 512 threads = 8 waves,
// 2 waves/SIMD.  Improvements over v5 (all within the 1-barrier structure):
//  - dual-buffer LDS addresses pre-baked in registers (rdo0/rdo1, wro0/wro1),
//    manual 2-step unroll -> zero per-step buffer-select VALU.
//  - hbar accumulation DEFERRED one step: executes in the next step's LDS
//    read-latency shadow instead of the pre-barrier critical path.
//  - phased gelu: chain(ft0) -> gelu+write ft0 overlaps chain(ft1) MFMA issue.
//  - chains split depth 8 -> 4 (2 accs/ftile) to cut exposed MFMA latency.
//  - kt-stagger: odd waves read/accumulate kt in reversed order (baked into
//    afr/rdo at init) to spread the post-barrier LDS burst.
// MFMA pipe floor: 128 mfma/step/CU ~620 cyc (structural).
// ---------------------------------------------------------------------------
__global__ __launch_bounds__(512, 2) void k_scan(const float* __restrict__ Am,
                                                 const bf16_t* __restrict__ u,
                                                 float* __restrict__ hbarOut) {
  __shared__ bf16_t HsF[2 * 16 * 256];  // [buf][sample][feature], XOR-swizzled
  const int b0 = blockIdx.x * 16;
  const int tid = threadIdx.x;
  const int wave = tid >> 6, lane = tid & 63, q = lane >> 4, l15 = lane & 15;
  const int rev = wave & 1;

  // A-frags in issue order i (kt = rev ? 7-i : i):
  // afr[ft][i] = A[f = wave*32+ft*16+l15][k = kt*32+q*8+e], e=0..7
  bf16x8 afr[2][8];
  int rdo0[8], rdo1[8];
  const int sw = l15 & 7;
#pragma unroll
  for (int i = 0; i < 8; ++i) {
    const int kt = rev ? 7 - i : i;
#pragma unroll
    for (int ft = 0; ft < 2; ++ft) {
      const int f = wave * 32 + ft * 16 + l15;
      const float* ap = Am + (size_t)f * 256 + kt * 32 + q * 8;
      f32x4 p0 = *(const f32x4*)ap;
      f32x4 p1 = *(const f32x4*)(ap + 4);
      bf16x8 v;
      v[0] = (bf16_t)p0[0]; v[1] = (bf16_t)p0[1]; v[2] = (bf16_t)p0[2]; v[3] = (bf16_t)p0[3];
      v[4] = (bf16_t)p1[0]; v[5] = (bf16_t)p1[1]; v[6] = (bf16_t)p1[2]; v[7] = (bf16_t)p1[3];
      afr[ft][i] = v;
    }
    rdo0[i] = l15 * 256 + (((kt * 4 + q) ^ sw) << 3);
    rdo1[i] = 4096 + rdo0[i];
  }
  // write: f0 = wave*32+ft*16+q*4 -> chunk c = wave*4+ft*2+(q>>1), half (q&1)*4
  int wro0[2], wro1[2];
#pragma unroll
  for (int ft = 0; ft < 2; ++ft) {
    wro0[ft] = l15 * 256 + (((wave * 4 + ft * 2 + (q >> 1)) ^ sw) << 3) + (q & 1) * 4;
    wro1[ft] = 4096 + wro0[ft];
  }
  for (int i = tid; i < 2 * 16 * 256 / 2; i += 512) ((int*)HsF)[i] = 0;

  // u: lane reads u[b0+l15][t][wave*32 + ft*16 + q*4 .. +3] (8B contiguous)
  const bf16_t* up = u + ((size_t)(b0 + l15) * 2048) * 256 + wave * 32 + q * 4;
  ushort4 uc[2], un[2];
#pragma unroll
  for (int ft = 0; ft < 2; ++ft) uc[ft] = *(const ushort4*)(up + ft * 16);
#pragma unroll
  for (int ft = 0; ft < 2; ++ft) un[ft] = *(const ushort4*)(up + 256 + ft * 16);

  f32x4 hbar0 = {0.f, 0.f, 0.f, 0.f}, hbar1 = {0.f, 0.f, 0.f, 0.f};
  f32x4 gprev0 = {0.f, 0.f, 0.f, 0.f}, gprev1 = {0.f, 0.f, 0.f, 0.f};
  const f32x4 z4 = {0.f, 0.f, 0.f, 0.f};
  __syncthreads();

  auto step = [&](const int* rdo, const int* wro, int t) __attribute__((always_inline)) {
    // h fragments for this step (critical path: issue first)
    bf16x8 hfr[8];
#pragma unroll
    for (int i = 0; i < 8; ++i) hfr[i] = *(const bf16x8*)&HsF[rdo[i]];
    // prefetch u for t+2 (stays in flight across the lgkm-only barrier)
    ushort4 u2[2];
    {
      size_t off = (size_t)(t + 2 <= 2047 ? t + 2 : 2047) * 256;
      u2[0] = *(const ushort4*)(up + off);
      u2[1] = *(const ushort4*)(up + off + 16);
    }
    // deferred hbar: previous step's g, executed in the read-latency shadow
    hbar0 += gprev0;
    hbar1 += gprev1;
    // 4 chains, depth 4
    f32x4 c0a = z4, c0b = z4, c1a = z4, c1b = z4;
#pragma unroll
    for (int i = 0; i < 4; ++i) {
      c0a = mfma16(afr[0][i], hfr[i], c0a);
      c1a = mfma16(afr[1][i], hfr[i], c1a);
    }
#pragma unroll
    for (int i = 4; i < 8; ++i) {
      c0b = mfma16(afr[0][i], hfr[i], c0b);
      c1b = mfma16(afr[1][i], hfr[i], c1b);
    }
    // ft0: combine, gelu, write (overlaps ft1 chain completion)
    f32x4 y0 = c0a + c0b;
    {
      float g0 = gelu_fast(y0[0] + bf2f(uc[0].x));
      float g1 = gelu_fast(y0[1] + bf2f(uc[0].y));
      float g2 = gelu_fast(y0[2] + bf2f(uc[0].z));
      float g3 = gelu_fast(y0[3] + bf2f(uc[0].w));
      bf16x4 pk;
      pk[0] = (bf16_t)g0; pk[1] = (bf16_t)g1; pk[2] = (bf16_t)g2; pk[3] = (bf16_t)g3;
      *(bf16x4*)&HsF[wro[0]] = pk;
      gprev0[0] = g0; gprev0[1] = g1; gprev0[2] = g2; gprev0[3] = g3;
    }
    f32x4 y1 = c1a + c1b;
    {
      float g0 = gelu_fast(y1[0] + bf2f(uc[1].x));
      float g1 = gelu_fast(y1[1] + bf2f(uc[1].y));
      float g2 = gelu_fast(y1[2] + bf2f(uc[1].z));
      float g3 = gelu_fast(y1[3] + bf2f(uc[1].w));
      bf16x4 pk;
      pk[0] = (bf16_t)g0; pk[1] = (bf16_t)g1; pk[2] = (bf16_t)g2; pk[3] = (bf16_t)g3;
      *(bf16x4*)&HsF[wro[1]] = pk;
      gprev1[0] = g0; gprev1[1] = g1; gprev1[2] = g2; gprev1[3] = g3;
    }
    // LDS-only drain + barrier: u prefetch stays outstanding across it.
    asm volatile("s_waitcnt lgkmcnt(0)\n\ts_barrier" ::: "memory");
    uc[0] = un[0]; uc[1] = un[1];
    un[0] = u2[0]; un[1] = u2[1];
  };

  for (int t = 0; t < 2048; t += 2) {
    step(rdo0, wro1, t);      // read buf0, write buf1
    step(rdo1, wro0, t + 1);  // read buf1, write buf0
  }
  hbar0 += gprev0;
  hbar1 += gprev1;

  // hbar[sample = b0+l15][feature f]
  {
    f32x4 v0, v1;
#pragma unroll
    for (int r = 0; r < 4; ++r) { v0[r] = hbar0[r] * (1.f / 2048.f); v1[r] = hbar1[r] * (1.f / 2048.f); }
    float* dst = hbarOut + (size_t)(b0 + l15) * 256 + wave * 32 + q * 4;
    *(f32x4*)(dst) = v0;
    *(f32x4*)(dst + 16) = v1;
  }
}

// ---------------------------------------------------------------------------
// k_meta: per-sample stats (mean, unbiased std over T for 6 channels) fused
// with metanet + frontdoor MLPs.  Writes conf_hat to out, adj to ws.
// ---------------------------------------------------------------------------
__global__ void k_meta(const float* __restrict__ M,
                       const float* __restrict__ w1, const float* __restrict__ b1,
                       const float* __restrict__ w2, const float* __restrict__ b2,
                       const float* __restrict__ w3, const float* __restrict__ b3,
                       const float* __restrict__ f1, const float* __restrict__ fb1,
                       const float* __restrict__ f2, const float* __restrict__ fb2,
                       float* __restrict__ out, float* __restrict__ adj) {
  const int b = blockIdx.x, tid = threadIdx.x;
  const int w = tid >> 6, lane = tid & 63;
  __shared__ float s[12], red[8], z1[64], z2[128], ch[64], a1[128];
  for (int c = 0; c < 6; ++c) {
    const float* p = M + ((size_t)b * 6 + c) * 2048;
    float sum = 0.f, ss = 0.f;
    for (int t = tid; t < 2048; t += 256) { float v = p[t]; sum += v; ss += v * v; }
    for (int o = 32; o > 0; o >>= 1) { sum += __shfl_down(sum, o, 64); ss += __shfl_down(ss, o, 64); }
    if (lane == 0) { red[w * 2] = sum; red[w * 2 + 1] = ss; }
    __syncthreads();
    if (tid == 0) {
      sum = red[0] + red[2] + red[4] + red[6];
      ss = red[1] + red[3] + red[5] + red[7];
      float mean = sum * (1.f / 2048.f);
      float var = (ss - 2048.f * mean * mean) * (1.f / 2047.f);
      if (var < 0.f) var = 0.f;
      s[c] = mean;
      s[6 + c] = sqrtf(var);
    }
    __syncthreads();
  }
  if (tid < 64) {
    float v = b1[tid];
    for (int e = 0; e < 12; ++e) v += w1[tid * 12 + e] * s[e];
    z1[tid] = v > 0.f ? v : 0.f;
  }
  __syncthreads();
  if (tid < 128) {
    float v = b2[tid];
    for (int e = 0; e < 64; ++e) v += w2[tid * 64 + e] * z1[e];
    z2[tid] = v > 0.f ? v : 0.f;
  }
  __syncthreads();
  if (tid < 64) {
    float v = b3[tid];
    for (int e = 0; e < 128; ++e) v += w3[tid * 128 + e] * z2[e];
    ch[tid] = v;
    out[16704 + b * 64 + tid] = v;  // conf_hat
  }
  __syncthreads();
  if (tid < 128) {
    float v = fb1[tid];
    for (int e = 0; e < 64; ++e) v += f1[tid * 64 + e] * ch[e];
    a1[tid] = v > 0.f ? v : 0.f;
  }
  __syncthreads();
  {
    float v = fb2[tid];
    for (int e = 0; e < 128; ++e) v += f2[tid * 128 + e] * a1[e];
    adj[b * 256 + tid] = v;
  }
}

// ---------------------------------------------------------------------------
// head: pooled = hbar @ op_w^T + op_b; corrected = pooled - adj;
// logits = relu(pooled@cls_w1^T+b)@cls_w2^T+b.
// ---------------------------------------------------------------------------
__global__ void k_head(const float* __restrict__ hbar, const float* __restrict__ op_w,
                       const float* __restrict__ op_b, const float* __restrict__ cw1,
                       const float* __restrict__ cb1, const float* __restrict__ cw2,
                       const float* __restrict__ cb2, const float* __restrict__ adj,
                       float* __restrict__ out) {
  const int b = blockIdx.x, g = threadIdx.x;
  __shared__ float hs[256], ps[256], hid[256];
  hs[g] = hbar[b * 256 + g];
  __syncthreads();
  float v = op_b[g];
  for (int h = 0; h < 256; ++h) v += op_w[g * 256 + h] * hs[h];
  out[320 + b * 256 + g] = v;                 // pooled
  out[8512 + b * 256 + g] = v - adj[b * 256 + g];  // corrected
  ps[g] = v;
  __syncthreads();
  float hv = cb1[g];
  for (int h = 0; h < 256; ++h) hv += cw1[g * 256 + h] * ps[h];
  hid[g] = hv > 0.f ? hv : 0.f;
  __syncthreads();
  if (g < 10) {
    float lv = cb2[g];
    for (int h = 0; h < 256; ++h) lv += cw2[g * 256 + h] * hid[h];
    out[b * 10 + g] = lv;  // logits
  }
}

// ---------------------------------------------------------------------------
extern "C" void kernel_launch(void* const* d_in, const int* in_sizes, int n_in,
                              void* d_out, int out_size, void* d_ws, size_t ws_size,
                              hipStream_t stream) {
  (void)in_sizes; (void)n_in; (void)out_size; (void)ws_size;
  const float* M    = (const float*)d_in[0];
  const float* w0   = (const float*)d_in[1];  const float* b0  = (const float*)d_in[2];
  const float* w1   = (const float*)d_in[3];  const float* b1  = (const float*)d_in[4];
  const float* w2   = (const float*)d_in[5];  const float* b2  = (const float*)d_in[6];
  const float* w3   = (const float*)d_in[7];  const float* b3  = (const float*)d_in[8];
  const float* encw = (const float*)d_in[9];  const float* encb = (const float*)d_in[10];
  const float* Am   = (const float*)d_in[11];
  const float* ipw  = (const float*)d_in[12]; const float* ipb = (const float*)d_in[13];
  const float* sb   = (const float*)d_in[14];
  const float* opw  = (const float*)d_in[15]; const float* opb = (const float*)d_in[16];
  const float* cw1  = (const float*)d_in[17]; const float* cb1 = (const float*)d_in[18];
  const float* cw2  = (const float*)d_in[19]; const float* cb2 = (const float*)d_in[20];
  const float* mw1  = (const float*)d_in[21]; const float* mb1 = (const float*)d_in[22];
  const float* mw2  = (const float*)d_in[23]; const float* mb2 = (const float*)d_in[24];
  const float* mw3  = (const float*)d_in[25]; const float* mb3 = (const float*)d_in[26];
  const float* fw1  = (const float*)d_in[27]; const float* fb1 = (const float*)d_in[28];
  const float* fw2  = (const float*)d_in[29]; const float* fb2 = (const float*)d_in[30];
  float* out = (float*)d_out;

  char* ws = (char*)d_ws;
  bf16_t* wb0  = (bf16_t*)(ws + 0);          // 8192
  bf16_t* wb1  = (bf16_t*)(ws + 8192);       // 163840
  bf16_t* wb2  = (bf16_t*)(ws + 172032);     // 163840
  bf16_t* wb3  = (bf16_t*)(ws + 335872);     // 163840
  bf16_t* wce  = (bf16_t*)(ws + 499712);     // 65536
  float*  bce  = (float*) (ws + 565248);     // 1024
  float*  hbar = (float*) (ws + 566272);     // 32768
  float*  adj  = (float*) (ws + 599040);     // 32768
  bf16_t* actA = (bf16_t*)(ws + 633856);     // 16 MB
  bf16_t* actB = (bf16_t*)(ws + 17411072);   // 16 MB
  bf16_t* u    = (bf16_t*)(ws + 34188288);   // 32 MB  (total ~64.6 MB)

  k_prep<<<1104, 256, 0, stream>>>(w0, w1, w2, w3, wb0, wb1, wb2, wb3,
                                   ipw, encw, encb, ipb, sb, wce, bce);
  k_conv0<<<dim3(16, 32), 256, 0, stream>>>(M, wb0, b0, actA);
  k_conv<2><<<dim3(16, 32), 256, 0, stream>>>(actA, wb1, b1, actB);
  k_conv<4><<<dim3(16, 32), 256, 0, stream>>>(actB, wb2, b2, actA);
  k_conv<8><<<dim3(16, 32), 256, 0, stream>>>(actA, wb3, b3, actB);
  k_ugemm<<<dim3(16, 32, 2), 256, 0, stream>>>(actB, wce, bce, u);
  k_scan<<<2, 512, 0, stream>>>(Am, u, hbar);
  k_meta<<<32, 256, 0, stream>>>(M, mw1, mb1, mw2, mb2, mw3, mb3,
                                 fw1, fb1, fw2, fb2, out, adj);
  k_head<<<32, 256, 0, stream>>>(hbar, opw, opb, cw1, cb1, cw2, cb2, adj, out);
}